// Round 5
// baseline (179.739 us; speedup 1.0000x reference)
//
#include <hip/hip_runtime.h>
#include <hip/hip_bf16.h>

// AttentionBlock: GroupNorm -> QKV -> MHA (8 heads, hd=64, s=1024) -> out proj -> +xn
// Inputs/outputs FP32; internally bf16 for MFMA.
//
// r17: GEMMs reverted to r15 exactly (r16's direct-B + launch_bounds(256,3)
// forced VGPR cap -> spills -> regression). attn: V LDS staging removed --
// PV B-frags read DIRECTLY from L2 (vT row d, two contiguous 8B true-key
// segments per frag under the sigma relabeling); deletes Vs buffers,
// loadV/writeV, and half of attn's LDS-read traffic (its binding pipe).
//
// ws: xn 8MB @0 | kq 16MB @8 | attn 8MB @24 | vT 8MB @32 | wqkvT 1.5MB @40 | woutT .5MB @41.5

#define B_    8
#define S_    1024
#define C_    512
#define NH    8
#define HD    64
#define QKVC  1536
#define GROUPS 32
#define GSIZE  16
#define EPSV   1e-5f
#define QSCL  0.18033688f   // 0.125 * log2(e)

using frag8 = __attribute__((ext_vector_type(8))) short;   // 8 bf16 = 4 VGPR
using f32x4 = __attribute__((ext_vector_type(4))) float;

__device__ __forceinline__ float bf2f(unsigned short u) {
    union { unsigned int i; float f; } v; v.i = ((unsigned int)u) << 16; return v.f;
}
__device__ __forceinline__ unsigned short f2bf(float f) {
    union { float f; unsigned int i; } v; v.f = f;
    unsigned int x = v.i;
    return (unsigned short)((x + 0x7fffu + ((x >> 16) & 1u)) >> 16);
}
// pack two fp32 -> two bf16 (round-half-up) in one dword: low=a, high=b
__device__ __forceinline__ unsigned int pk2bf(float a, float b) {
    union { float f; unsigned int u; } x, y; x.f = a; y.f = b;
    return __builtin_amdgcn_perm(y.u + 0x8000u, x.u + 0x8000u, 0x07060302u);
}
__device__ __forceinline__ float fexp2(float x) {
#if __has_builtin(__builtin_amdgcn_exp2f)
    return __builtin_amdgcn_exp2f(x);
#else
    return exp2f(x);
#endif
}
__device__ __forceinline__ f32x4 zero4() {
    f32x4 z; z[0] = 0.f; z[1] = 0.f; z[2] = 0.f; z[3] = 0.f; return z;
}
__device__ __forceinline__ void gl_lds(const unsigned short* gp, unsigned short* lp) {
    __builtin_amdgcn_global_load_lds(
        (const __attribute__((address_space(1))) void*)gp,
        (__attribute__((address_space(3))) void*)lp, 16, 0, 0);
}

// ---------------------------------------------------------------- prep
// blocks 0..767: transpose w_qkv; 768..1023: transpose w_out; 1024..1279: gn
__global__ __launch_bounds__(256) void prep_kernel(
        const float* __restrict__ w_qkv, const float* __restrict__ w_out,
        unsigned short* __restrict__ wqkvT, unsigned short* __restrict__ woutT,
        const float* __restrict__ x,
        const float* __restrict__ scale, const float* __restrict__ bias,
        unsigned short* __restrict__ xn) {
    __shared__ unsigned short xcache[16384];     // gn: bf16 x cache (32 KB)
    __shared__ float s_red[8];
    int id = blockIdx.x;
    int t = threadIdx.x;
    if (id < 1024) {
        float* tile = (float*)xcache;            // reuse as 32x33 fp32 tile
        const float* in; unsigned short* out; int N, n0, k0;
        if (id < 768) { in = w_qkv; out = wqkvT; N = QKVC; n0 = (id % 48) * 32; k0 = (id / 48) * 32; }
        else { int i2 = id - 768; in = w_out; out = woutT; N = C_; n0 = (i2 % 16) * 32; k0 = (i2 / 16) * 32; }
        for (int i = 0; i < 4; ++i) {
            int idx = t + i * 256; int r = idx >> 5, c = idx & 31;
            tile[r * 33 + c] = in[(size_t)(k0 + r) * N + n0 + c];
        }
        __syncthreads();
        for (int i = 0; i < 2; ++i) {
            int idx = t + i * 256;               // 0..511
            int r = idx >> 4, c2 = (idx & 15) * 2;
            unsigned int pk = pk2bf(tile[c2 * 33 + r], tile[(c2 + 1) * 33 + r]);
            *(unsigned int*)(&out[(size_t)(n0 + r) * C_ + k0 + c2]) = pk;
        }
        return;
    }
    // ---- groupnorm: pass 1 reads fp32 x, sums, caches bf16 in LDS;
    //      pass 2 normalizes from LDS (x read from HBM exactly once).
    // Block remap: colocate (b, 2j) and (b, 2j+1) on the same XCD so each
    // 128B x-line (two adjacent 16ch groups) is fetched by one XCD only.
    int s = id - 1024;                           // 0..255; id%8 == s%8 (1024%8==0)
    int xcd = s & 7, u = s >> 3;                 // u 0..31
    int gp = xcd * 16 + (u >> 1);                // global group-pair 0..127
    int b = gp >> 4, g = ((gp & 15) << 1) | (u & 1);
    const float* xb = x + (size_t)b * S_ * C_;

    float sum = 0.f, ss = 0.f;
    for (int i = 0; i < 16; ++i) {
        int idx = t + i * 256;                   // 0..4095 float4 segments
        int row = idx >> 2, j = idx & 3;
        float4 v = *(const float4*)(xb + (size_t)row * C_ + g * GSIZE + j * 4);
        sum += v.x + v.y + v.z + v.w;
        ss  += v.x * v.x + v.y * v.y + v.z * v.z + v.w * v.w;
        uint2 c;
        c.x = pk2bf(v.x, v.y);
        c.y = pk2bf(v.z, v.w);
        *(uint2*)(&xcache[idx * 4]) = c;
    }
    for (int off = 1; off < 64; off <<= 1) {
        sum += __shfl_xor(sum, off);
        ss  += __shfl_xor(ss,  off);
    }
    int wid = t >> 6;
    if ((t & 63) == 0) { s_red[wid] = sum; s_red[4 + wid] = ss; }
    __syncthreads();
    sum = s_red[0] + s_red[1] + s_red[2] + s_red[3];
    ss  = s_red[4] + s_red[5] + s_red[6] + s_red[7];
    float mean = sum * (1.f / 16384.f);
    float var  = ss * (1.f / 16384.f) - mean * mean;
    float rinv = rsqrtf(var + EPSV);

    float sc[16], bi[16];
    for (int u2 = 0; u2 < 16; ++u2) {
        sc[u2] = scale[g * GSIZE + u2];
        bi[u2] = bias[g * GSIZE + u2];
    }
    for (int i = 0; i < 16; ++i) {
        int idx = t + i * 256;
        int row = idx >> 2, j = idx & 3;
        uint2 c = *(const uint2*)(&xcache[idx * 4]);
        float v0 = bf2f((unsigned short)(c.x & 0xffffu));
        float v1 = bf2f((unsigned short)(c.x >> 16));
        float v2 = bf2f((unsigned short)(c.y & 0xffffu));
        float v3 = bf2f((unsigned short)(c.y >> 16));
        int c0 = j * 4;
        float f0 = (v0 - mean) * rinv * sc[c0 + 0] + bi[c0 + 0];
        float f1 = (v1 - mean) * rinv * sc[c0 + 1] + bi[c0 + 1];
        float f2 = (v2 - mean) * rinv * sc[c0 + 2] + bi[c0 + 2];
        float f3 = (v3 - mean) * rinv * sc[c0 + 3] + bi[c0 + 3];
        uint2 o;
        o.x = pk2bf(f0, f1);
        o.y = pk2bf(f2, f3);
        *(uint2*)(xn + (size_t)b * S_ * C_ + (size_t)row * C_ + g * GSIZE + c0) = o;
    }
}

// ---------------------------------------------------------------- QKV GEMM
// 128x128 tile, BK=32, A+B via global_load_lds, double-buffered.
// XCD swizzle: 768 blocks -> each XCD owns 8 m-tiles x 12 n-tiles.
// T2 seg-swizzle: LDS[row][seg] holds G[row][seg ^ ((row>>1)&3)]
// (applied on the gl_lds global source; read side XORs the same term).
__global__ __launch_bounds__(256) void gemm_qkv_kernel(
        const unsigned short* __restrict__ A,     // xn [8192][512]
        const unsigned short* __restrict__ Bt,    // wqkvT [1536][512]
        const float* __restrict__ bias,
        unsigned short* __restrict__ outA,        // kq [M][1024]
        unsigned short* __restrict__ outV) {      // vT [b][h][64][1024]
    __shared__ unsigned short As[2][128 * 32];
    __shared__ unsigned short Bs[2][128 * 32];
    unsigned int flat = blockIdx.y * 12u + blockIdx.x;
    unsigned int nid = (flat & 7u) * 96u + (flat >> 3);   // bijective (768%8==0)
    int my = nid / 12u, mx = nid % 12u;
    int m0 = my * 128, n0 = mx * 128;
    int t = threadIdx.x;
    int wid = t >> 6, lane = t & 63;
    int quad = lane >> 4, l16 = lane & 15;
    int wm = (wid >> 1) * 64, wn = (wid & 1) * 64;

    f32x4 acc[4][4];
    for (int mi = 0; mi < 4; ++mi)
        for (int ni = 0; ni < 4; ++ni) acc[mi][ni] = zero4();

    int srow = t >> 2;                            // staging row-within-64
    int sseg_sw = (t & 3) ^ ((t >> 3) & 3);       // pre-swizzled global seg
    auto stage = [&](int k0, int buf) {
        for (int i = 0; i < 2; ++i) {
            gl_lds(A + (size_t)(m0 + i * 64 + srow) * C_ + k0 + sseg_sw * 8,
                   &As[buf][(size_t)(i * 256 + wid * 64) * 8]);
            gl_lds(Bt + (size_t)(n0 + i * 64 + srow) * C_ + k0 + sseg_sw * 8,
                   &Bs[buf][(size_t)(i * 256 + wid * 64) * 8]);
        }
    };

    int rsw8 = ((l16 >> 1) & 3) * 8;              // read-side swizzle (shorts)

    stage(0, 0);
    const int nk = C_ >> 5;                      // 16
    for (int i = 0; i < nk; ++i) {
        __syncthreads();
        if (i + 1 < nk) stage((i + 1) << 5, (i + 1) & 1);
        int buf = i & 1;

        frag8 bfrag[4], afrag[4];
        for (int ni = 0; ni < 4; ++ni)
            bfrag[ni] = *(const frag8*)(&Bs[buf][(wn + ni * 16 + l16) * 32 + ((quad * 8) ^ rsw8)]);
        for (int mi = 0; mi < 4; ++mi)
            afrag[mi] = *(const frag8*)(&As[buf][(wm + mi * 16 + l16) * 32 + ((quad * 8) ^ rsw8)]);

        for (int mi = 0; mi < 4; ++mi)
            for (int ni = 0; ni < 4; ++ni)
                acc[mi][ni] = __builtin_amdgcn_mfma_f32_16x16x32_bf16(
                    afrag[mi], bfrag[ni], acc[mi][ni], 0, 0, 0);
    }

    for (int ni = 0; ni < 4; ++ni) {
        int c0 = n0 + wn + ni * 16;
        float bv = bias[c0 + l16];
        int h = c0 / 192, rr = c0 % 192;
        if (rr >= 128) {
            int d = rr - 128 + l16;
            int bidx = m0 >> 10;
            unsigned short* vp = outV + (((size_t)bidx * NH + h) * HD + d) * S_
                               + (m0 & 1023) + wm + quad * 4;
            for (int mi = 0; mi < 4; ++mi) {
                uint2 pk;
                pk.x = pk2bf(acc[mi][ni][0] + bv, acc[mi][ni][1] + bv);
                pk.y = pk2bf(acc[mi][ni][2] + bv, acc[mi][ni][3] + bv);
                *(uint2*)(vp + mi * 16) = pk;
            }
        } else {
            float scl = (rr < 64) ? QSCL : 1.0f;   // q pre-scaled by log2e/8
            int colk = h * 128 + rr + l16;
            for (int mi = 0; mi < 4; ++mi)
                for (int r = 0; r < 4; ++r) {
                    int row = m0 + wm + mi * 16 + quad * 4 + r;
                    outA[(size_t)row * 1024 + colk] = f2bf((acc[mi][ni][r] + bv) * scl);
                }
        }
    }
}

// ---------------------------------------------------------------- out GEMM
// 64x128 tile, 512 blocks = 2/CU. BK=64 per barrier as two 32-wide
// sub-steps (4-buffer LDS, 48 KB) -> 8 barriers; gl_lds staging
// seg-swizzled; fused bias + residual, fp32 out.
__global__ __launch_bounds__(256) void gemm_out_kernel(
        const unsigned short* __restrict__ A,     // attn [8192][512]
        const unsigned short* __restrict__ Bt,    // woutT [512][512]
        const float* __restrict__ bias,
        const unsigned short* __restrict__ resid, // xn
        float* __restrict__ outF) {
    __shared__ unsigned short As[2][2][64 * 32];
    __shared__ unsigned short Bs[2][2][128 * 32];
    unsigned int flat = blockIdx.x;
    unsigned int nid = (flat & 7u) * 64u + (flat >> 3);   // bijective (512%8==0)
    int my = nid >> 2, mx = nid & 3;
    int m0 = my * 64, n0 = mx * 128;
    int t = threadIdx.x;
    int wid = t >> 6, lane = t & 63;
    int quad = lane >> 4, l16 = lane & 15;
    int wm = (wid >> 1) * 32, wn = (wid & 1) * 64;

    f32x4 acc[2][4];
    for (int mi = 0; mi < 2; ++mi)
        for (int ni = 0; ni < 4; ++ni) acc[mi][ni] = zero4();

    int srow = t >> 2;
    int sseg_sw = (t & 3) ^ ((t >> 3) & 3);
    auto stage = [&](int k0, int buf) {
        for (int s = 0; s < 2; ++s) {
            gl_lds(A + (size_t)(m0 + srow) * C_ + k0 + s * 32 + sseg_sw * 8,
                   &As[buf][s][(size_t)wid * 512]);
            for (int i = 0; i < 2; ++i)
                gl_lds(Bt + (size_t)(n0 + i * 64 + srow) * C_ + k0 + s * 32 + sseg_sw * 8,
                       &Bs[buf][s][(size_t)(i * 256 + wid * 64) * 8]);
        }
    };

    int rsw8 = ((l16 >> 1) & 3) * 8;

    stage(0, 0);
    const int nk = C_ >> 6;                      // 8 (BK=64 per barrier)
    for (int i = 0; i < nk; ++i) {
        __syncthreads();
        if (i + 1 < nk) stage((i + 1) << 6, (i + 1) & 1);
        int buf = i & 1;

        for (int s = 0; s < 2; ++s) {
            frag8 bfrag[4], afrag[2];
            for (int ni = 0; ni < 4; ++ni)
                bfrag[ni] = *(const frag8*)(&Bs[buf][s][(wn + ni * 16 + l16) * 32 + ((quad * 8) ^ rsw8)]);
            for (int mi = 0; mi < 2; ++mi)
                afrag[mi] = *(const frag8*)(&As[buf][s][(wm + mi * 16 + l16) * 32 + ((quad * 8) ^ rsw8)]);

            for (int mi = 0; mi < 2; ++mi)
                for (int ni = 0; ni < 4; ++ni)
                    acc[mi][ni] = __builtin_amdgcn_mfma_f32_16x16x32_bf16(
                        afrag[mi], bfrag[ni], acc[mi][ni], 0, 0, 0);
        }
    }

    for (int ni = 0; ni < 4; ++ni) {
        int col = n0 + wn + ni * 16 + l16;
        float bv = bias[col];
        for (int mi = 0; mi < 2; ++mi)
            for (int r = 0; r < 4; ++r) {
                int row = m0 + wm + mi * 16 + quad * 4 + r;
                float v = acc[mi][ni][r] + bv + bf2f(resid[(size_t)row * C_ + col]);
                outF[(size_t)row * C_ + col] = v;
            }
    }
}

// ---------------------------------------------------------------- attention
// 512 blocks (XCD-chunked), 4 waves x 32 q-rows (128 q/block), 64 keys/iter.
// Core: S^T=K@Q^T, P built in registers as PV A-frag under key relabeling
// sigma(kh,quad,r)=8*quad+4*kh+r. K staged in LDS (16B-seg XOR swizzle,
// double-buffered gl_lds). r17: V read DIRECTLY from L2 -- PV B-frag slot
// j of lane(quad,l16) = V[d=dt*16+l16][s0+quad*4+j | s0+16+quad*4+(j-4)],
// i.e. two contiguous 8B segments of a vT row; no Vs LDS, no writeV.
// l on VALU from packed P frag; quad-reduce at epilogue. No ones-MFMA.
__global__ __launch_bounds__(256) void attn_kernel(
        const unsigned short* __restrict__ kq,   // [b*s][h*128 + (q|k)]
        const unsigned short* __restrict__ vT,   // [b][h][d][s]
        unsigned short* __restrict__ attn_out) { // [b][s][512]
    int i = blockIdx.x;
    int xcd = i & 7, slot = i >> 3;              // slot 0..63
    int bh = xcd * 8 + (slot >> 3);              // 8 (b,h) pairs per XCD
    int qt = slot & 7;                           // 8 q-tiles of 128
    int b = bh >> 3, h = bh & 7;

    int t = threadIdx.x;
    int wid = t >> 6, lane = t & 63, quad = lane >> 4, l16 = lane & 15;
    int q0 = qt * 128 + wid * 32;

    __shared__ unsigned short Ks[2][2][2048];    // [buf][key-half 32][dh][key32][seg4x8] (swz)

    // Q B-fragments for both 16-row groups (one-time scattered load)
    const unsigned short* qrow0 = kq + ((size_t)b * S_ + q0 + l16) * 1024 + h * 128;
    const unsigned short* qrow1 = qrow0 + (size_t)16 * 1024;
    frag8 qf[2][2];
    qf[0][0] = *(const frag8*)(qrow0 + quad * 8);
    qf[0][1] = *(const frag8*)(qrow0 + 32 + quad * 8);
    qf[1][0] = *(const frag8*)(qrow1 + quad * 8);
    qf[1][1] = *(const frag8*)(qrow1 + 32 + quad * 8);

    f32x4 o[2][4];
    float lsum[2] = {0.f, 0.f};
    for (int g = 0; g < 2; ++g)
        for (int dt = 0; dt < 4; ++dt) o[g][dt] = zero4();

    const unsigned short* kbase = kq + (size_t)b * S_ * 1024 + h * 128 + 64;
    const unsigned short* vbase = vT + ((size_t)b * NH + h) * HD * S_;
    // per-lane V row base for PV B-frags (row d = dt*16+l16, seg at quad*4)
    const unsigned short* vfb = vbase + (size_t)l16 * S_ + quad * 4;

    // K staging roles (gl_lds, wave-uniform linear LDS dest; fetch seg
    // permuted so LDS lands swizzled: seg_fetch = slot ^ ((local_row>>1)&3))
    int kdh = wid & 1, krh = wid >> 1;
    int krow = krh * 16 + (lane >> 2);
    int kseg = (lane & 3) ^ ((lane >> 3) & 3);

    int ksw = (l16 >> 1) & 3;                    // read-side swizzle

    auto stageK = [&](int j0, int buf, int half) {
        gl_lds(kbase + (size_t)(j0 + krow) * 1024 + kdh * 32 + kseg * 8,
               &Ks[buf][half][kdh * 1024 + krh * 512]);
    };

    stageK(0, 0, 0);  stageK(32, 0, 1);

    for (int it = 0; it < S_ / 64; ++it) {
        int cur = it & 1, nxt = cur ^ 1;
        __syncthreads();                          // staging of cur visible
        bool more = (it < S_ / 64 - 1);
        if (more) {
            int jn = (it + 1) * 64;
            stageK(jn, nxt, 0);
            stageK(jn + 32, nxt, 1);
        }

#pragma unroll
        for (int half = 0; half < 2; ++half) {
            int s0 = it * 64 + half * 32;

            // V B-frags direct from L2: slot j<4 = V[d][s0+quad*4+j],
            // j>=4 = V[d][s0+16+quad*4+(j-4)]  (issued first to hide latency)
            frag8 vf[4];
#pragma unroll
            for (int dt = 0; dt < 4; ++dt) {
                union { frag8 f; uint2 u[2]; } vv;
                const unsigned short* vrow = vfb + (size_t)(dt * 16) * S_ + s0;
                vv.u[0] = *(const uint2*)(vrow);
                vv.u[1] = *(const uint2*)(vrow + 16);
                vf[dt] = vv.f;
            }

            // K frags from LDS (A-operand): A[m=key=kh*16+l16][k=d] (swz read)
            frag8 kf[2][2];
#pragma unroll
            for (int kh = 0; kh < 2; ++kh)
#pragma unroll
                for (int dh = 0; dh < 2; ++dh)
                    kf[kh][dh] = *(const frag8*)(&Ks[cur][half][dh * 1024
                        + (kh * 16 + l16) * 32 + ((quad ^ ksw) * 8)]);

#pragma unroll
            for (int g = 0; g < 2; ++g) {
                // S^T = K @ Q^T : lane holds S^T[key=kh*16+quad*4+r][q=l16]
                f32x4 s0v = zero4(), s1v = zero4();
                __builtin_amdgcn_s_setprio(1);
                s0v = __builtin_amdgcn_mfma_f32_16x16x32_bf16(kf[0][0], qf[g][0], s0v, 0, 0, 0);
                s0v = __builtin_amdgcn_mfma_f32_16x16x32_bf16(kf[0][1], qf[g][1], s0v, 0, 0, 0);
                s1v = __builtin_amdgcn_mfma_f32_16x16x32_bf16(kf[1][0], qf[g][0], s1v, 0, 0, 0);
                s1v = __builtin_amdgcn_mfma_f32_16x16x32_bf16(kf[1][1], qf[g][1], s1v, 0, 0, 0);
                __builtin_amdgcn_s_setprio(0);

                // P A-frag in registers (relabeled positions)
                union { frag8 f; unsigned int u[4]; } pfu;
                pfu.u[0] = pk2bf(fexp2(s0v[0]), fexp2(s0v[1]));
                pfu.u[1] = pk2bf(fexp2(s0v[2]), fexp2(s0v[3]));
                pfu.u[2] = pk2bf(fexp2(s1v[0]), fexp2(s1v[1]));
                pfu.u[3] = pk2bf(fexp2(s1v[2]), fexp2(s1v[3]));

                // l partial on VALU: lane's 8 rounded P values belong to
                // q-row l16, keys quad*8+j (quad-reduce deferred to epilogue)
                float lacc = 0.f;
#pragma unroll
                for (int w2 = 0; w2 < 4; ++w2) {
                    union { unsigned int u; float f; } plo, phi;
                    plo.u = pfu.u[w2] << 16;
                    phi.u = pfu.u[w2] & 0xffff0000u;
                    lacc += plo.f + phi.f;
                }
                lsum[g] += lacc;

                __builtin_amdgcn_s_setprio(1);
#pragma unroll
                for (int dt = 0; dt < 4; ++dt)
                    o[g][dt] = __builtin_amdgcn_mfma_f32_16x16x32_bf16(pfu.f, vf[dt], o[g][dt], 0, 0, 0);
                __builtin_amdgcn_s_setprio(0);
            }
        }
    }

    // O C-layout: lane(quad,l16) holds O[q=g*16+quad*4+r][d=dt*16+l16].
    // lsum[g] holds the partial row-sum for q=l16 over this lane's quad's
    // key slots; reduce across quads, then fetch the value for row quad*4+r.
    for (int g = 0; g < 2; ++g) {
        float lq = lsum[g];
        lq += __shfl_xor(lq, 16);
        lq += __shfl_xor(lq, 32);                // all lanes: l[q=l16]
        for (int r = 0; r < 4; ++r) {
            float inv = 1.0f / __shfl(lq, quad * 4 + r);
            int qrw = q0 + g * 16 + quad * 4 + r;
            for (int dt = 0; dt < 4; ++dt) {
                int ch = h * HD + dt * 16 + l16;
                attn_out[((size_t)b * S_ + qrw) * C_ + ch] = f2bf(o[g][dt][r] * inv);
            }
        }
    }
}

// ---------------------------------------------------------------- launch
extern "C" void kernel_launch(void* const* d_in, const int* in_sizes, int n_in,
                              void* d_out, int out_size, void* d_ws, size_t ws_size,
                              hipStream_t stream) {
    const float* x        = (const float*)d_in[0];
    const float* gn_scale = (const float*)d_in[2];
    const float* gn_bias  = (const float*)d_in[3];
    const float* w_qkv    = (const float*)d_in[4];
    const float* b_qkv    = (const float*)d_in[5];
    const float* w_out    = (const float*)d_in[6];
    const float* b_out    = (const float*)d_in[7];
    float* out = (float*)d_out;

    char* ws = (char*)d_ws;
    unsigned short* xn    = (unsigned short*)(ws);                          // 8 MB
    unsigned short* kq    = (unsigned short*)(ws + ((size_t)8  << 20));     // 16 MB
    unsigned short* attn  = (unsigned short*)(ws + ((size_t)24 << 20));     // 8 MB
    unsigned short* vT    = (unsigned short*)(ws + ((size_t)32 << 20));     // 8 MB
    unsigned short* wqkvT = (unsigned short*)(ws + ((size_t)40 << 20));     // 1.5 MB
    unsigned short* woutT = (unsigned short*)(ws + ((size_t)40 << 20) + ((size_t)3 << 19)); // 0.5 MB

    prep_kernel<<<dim3(1280), 256, 0, stream>>>(
        w_qkv, w_out, wqkvT, woutT, x, gn_scale, gn_bias, xn);

    gemm_qkv_kernel<<<dim3(QKVC / 128, (B_ * S_) / 128), 256, 0, stream>>>(
        xn, wqkvT, b_qkv, kq, vT);

    attn_kernel<<<dim3(512), 256, 0, stream>>>(kq, vT, attn);

    gemm_out_kernel<<<dim3(512), 256, 0, stream>>>(
        attn, woutT, b_out, xn, out);
}

// Round 6
// 146.913 us; speedup vs baseline: 1.2234x; 1.2234x over previous
//
#include <hip/hip_runtime.h>
#include <hip/hip_bf16.h>

// AttentionBlock: GroupNorm -> QKV -> MHA (8 heads, hd=64, s=1024) -> out proj -> +xn
// Inputs/outputs FP32; internally bf16 for MFMA.
//
// r18 == r15 (best-known, 147.9us). r16 (direct-B GEMM) regressed via VGPR
// spills; r17 (direct-L2 V in attn) regressed via scattered per-lane 8B
// gathers + unhidden L2 latency (attn 67us, MfmaUtil 9.3%). Both reverted.
//
// r15 state: (1) attn: 32q/wave, K/V LDS 16B-seg XOR swizzle, l on VALU from
// packed P frag (no ones-MFMA), setprio around MFMA clusters; (2) qkv GEMM:
// 128x128 BK=32 dbuf gl_lds A+B, seg-swizzled, XCD-chunked; (3) out GEMM:
// 64x128, BK=64/barrier as two 32-substeps, seg-swizzled; (4) prep: gn
// XCD-colocated group pairs, dword-packed transpose stores.
//
// ws: xn 8MB @0 | kq 16MB @8 | attn 8MB @24 | vT 8MB @32 | wqkvT 1.5MB @40 | woutT .5MB @41.5

#define B_    8
#define S_    1024
#define C_    512
#define NH    8
#define HD    64
#define QKVC  1536
#define GROUPS 32
#define GSIZE  16
#define EPSV   1e-5f
#define QSCL  0.18033688f   // 0.125 * log2(e)

using frag8 = __attribute__((ext_vector_type(8))) short;   // 8 bf16 = 4 VGPR
using f32x4 = __attribute__((ext_vector_type(4))) float;

__device__ __forceinline__ float bf2f(unsigned short u) {
    union { unsigned int i; float f; } v; v.i = ((unsigned int)u) << 16; return v.f;
}
__device__ __forceinline__ unsigned short f2bf(float f) {
    union { float f; unsigned int i; } v; v.f = f;
    unsigned int x = v.i;
    return (unsigned short)((x + 0x7fffu + ((x >> 16) & 1u)) >> 16);
}
// pack two fp32 -> two bf16 (round-half-up) in one dword: low=a, high=b
__device__ __forceinline__ unsigned int pk2bf(float a, float b) {
    union { float f; unsigned int u; } x, y; x.f = a; y.f = b;
    return __builtin_amdgcn_perm(y.u + 0x8000u, x.u + 0x8000u, 0x07060302u);
}
__device__ __forceinline__ float fexp2(float x) {
#if __has_builtin(__builtin_amdgcn_exp2f)
    return __builtin_amdgcn_exp2f(x);
#else
    return exp2f(x);
#endif
}
__device__ __forceinline__ f32x4 zero4() {
    f32x4 z; z[0] = 0.f; z[1] = 0.f; z[2] = 0.f; z[3] = 0.f; return z;
}
__device__ __forceinline__ void gl_lds(const unsigned short* gp, unsigned short* lp) {
    __builtin_amdgcn_global_load_lds(
        (const __attribute__((address_space(1))) void*)gp,
        (__attribute__((address_space(3))) void*)lp, 16, 0, 0);
}

// ---------------------------------------------------------------- prep
// blocks 0..767: transpose w_qkv; 768..1023: transpose w_out; 1024..1279: gn
__global__ __launch_bounds__(256) void prep_kernel(
        const float* __restrict__ w_qkv, const float* __restrict__ w_out,
        unsigned short* __restrict__ wqkvT, unsigned short* __restrict__ woutT,
        const float* __restrict__ x,
        const float* __restrict__ scale, const float* __restrict__ bias,
        unsigned short* __restrict__ xn) {
    __shared__ unsigned short xcache[16384];     // gn: bf16 x cache (32 KB)
    __shared__ float s_red[8];
    int id = blockIdx.x;
    int t = threadIdx.x;
    if (id < 1024) {
        float* tile = (float*)xcache;            // reuse as 32x33 fp32 tile
        const float* in; unsigned short* out; int N, n0, k0;
        if (id < 768) { in = w_qkv; out = wqkvT; N = QKVC; n0 = (id % 48) * 32; k0 = (id / 48) * 32; }
        else { int i2 = id - 768; in = w_out; out = woutT; N = C_; n0 = (i2 % 16) * 32; k0 = (i2 / 16) * 32; }
        for (int i = 0; i < 4; ++i) {
            int idx = t + i * 256; int r = idx >> 5, c = idx & 31;
            tile[r * 33 + c] = in[(size_t)(k0 + r) * N + n0 + c];
        }
        __syncthreads();
        for (int i = 0; i < 2; ++i) {
            int idx = t + i * 256;               // 0..511
            int r = idx >> 4, c2 = (idx & 15) * 2;
            unsigned int pk = pk2bf(tile[c2 * 33 + r], tile[(c2 + 1) * 33 + r]);
            *(unsigned int*)(&out[(size_t)(n0 + r) * C_ + k0 + c2]) = pk;
        }
        return;
    }
    // ---- groupnorm: pass 1 reads fp32 x, sums, caches bf16 in LDS;
    //      pass 2 normalizes from LDS (x read from HBM exactly once).
    // Block remap: colocate (b, 2j) and (b, 2j+1) on the same XCD so each
    // 128B x-line (two adjacent 16ch groups) is fetched by one XCD only.
    int s = id - 1024;                           // 0..255; id%8 == s%8 (1024%8==0)
    int xcd = s & 7, u = s >> 3;                 // u 0..31
    int gp = xcd * 16 + (u >> 1);                // global group-pair 0..127
    int b = gp >> 4, g = ((gp & 15) << 1) | (u & 1);
    const float* xb = x + (size_t)b * S_ * C_;

    float sum = 0.f, ss = 0.f;
    for (int i = 0; i < 16; ++i) {
        int idx = t + i * 256;                   // 0..4095 float4 segments
        int row = idx >> 2, j = idx & 3;
        float4 v = *(const float4*)(xb + (size_t)row * C_ + g * GSIZE + j * 4);
        sum += v.x + v.y + v.z + v.w;
        ss  += v.x * v.x + v.y * v.y + v.z * v.z + v.w * v.w;
        uint2 c;
        c.x = pk2bf(v.x, v.y);
        c.y = pk2bf(v.z, v.w);
        *(uint2*)(&xcache[idx * 4]) = c;
    }
    for (int off = 1; off < 64; off <<= 1) {
        sum += __shfl_xor(sum, off);
        ss  += __shfl_xor(ss,  off);
    }
    int wid = t >> 6;
    if ((t & 63) == 0) { s_red[wid] = sum; s_red[4 + wid] = ss; }
    __syncthreads();
    sum = s_red[0] + s_red[1] + s_red[2] + s_red[3];
    ss  = s_red[4] + s_red[5] + s_red[6] + s_red[7];
    float mean = sum * (1.f / 16384.f);
    float var  = ss * (1.f / 16384.f) - mean * mean;
    float rinv = rsqrtf(var + EPSV);

    float sc[16], bi[16];
    for (int u2 = 0; u2 < 16; ++u2) {
        sc[u2] = scale[g * GSIZE + u2];
        bi[u2] = bias[g * GSIZE + u2];
    }
    for (int i = 0; i < 16; ++i) {
        int idx = t + i * 256;
        int row = idx >> 2, j = idx & 3;
        uint2 c = *(const uint2*)(&xcache[idx * 4]);
        float v0 = bf2f((unsigned short)(c.x & 0xffffu));
        float v1 = bf2f((unsigned short)(c.x >> 16));
        float v2 = bf2f((unsigned short)(c.y & 0xffffu));
        float v3 = bf2f((unsigned short)(c.y >> 16));
        int c0 = j * 4;
        float f0 = (v0 - mean) * rinv * sc[c0 + 0] + bi[c0 + 0];
        float f1 = (v1 - mean) * rinv * sc[c0 + 1] + bi[c0 + 1];
        float f2 = (v2 - mean) * rinv * sc[c0 + 2] + bi[c0 + 2];
        float f3 = (v3 - mean) * rinv * sc[c0 + 3] + bi[c0 + 3];
        uint2 o;
        o.x = pk2bf(f0, f1);
        o.y = pk2bf(f2, f3);
        *(uint2*)(xn + (size_t)b * S_ * C_ + (size_t)row * C_ + g * GSIZE + c0) = o;
    }
}

// ---------------------------------------------------------------- QKV GEMM
// 128x128 tile, BK=32, A+B via global_load_lds, double-buffered.
// XCD swizzle: 768 blocks -> each XCD owns 8 m-tiles x 12 n-tiles.
// T2 seg-swizzle: LDS[row][seg] holds G[row][seg ^ ((row>>1)&3)]
// (applied on the gl_lds global source; read side XORs the same term).
__global__ __launch_bounds__(256) void gemm_qkv_kernel(
        const unsigned short* __restrict__ A,     // xn [8192][512]
        const unsigned short* __restrict__ Bt,    // wqkvT [1536][512]
        const float* __restrict__ bias,
        unsigned short* __restrict__ outA,        // kq [M][1024]
        unsigned short* __restrict__ outV) {      // vT [b][h][64][1024]
    __shared__ unsigned short As[2][128 * 32];
    __shared__ unsigned short Bs[2][128 * 32];
    unsigned int flat = blockIdx.y * 12u + blockIdx.x;
    unsigned int nid = (flat & 7u) * 96u + (flat >> 3);   // bijective (768%8==0)
    int my = nid / 12u, mx = nid % 12u;
    int m0 = my * 128, n0 = mx * 128;
    int t = threadIdx.x;
    int wid = t >> 6, lane = t & 63;
    int quad = lane >> 4, l16 = lane & 15;
    int wm = (wid >> 1) * 64, wn = (wid & 1) * 64;

    f32x4 acc[4][4];
    for (int mi = 0; mi < 4; ++mi)
        for (int ni = 0; ni < 4; ++ni) acc[mi][ni] = zero4();

    int srow = t >> 2;                            // staging row-within-64
    int sseg_sw = (t & 3) ^ ((t >> 3) & 3);       // pre-swizzled global seg
    auto stage = [&](int k0, int buf) {
        for (int i = 0; i < 2; ++i) {
            gl_lds(A + (size_t)(m0 + i * 64 + srow) * C_ + k0 + sseg_sw * 8,
                   &As[buf][(size_t)(i * 256 + wid * 64) * 8]);
            gl_lds(Bt + (size_t)(n0 + i * 64 + srow) * C_ + k0 + sseg_sw * 8,
                   &Bs[buf][(size_t)(i * 256 + wid * 64) * 8]);
        }
    };

    int rsw8 = ((l16 >> 1) & 3) * 8;              // read-side swizzle (shorts)

    stage(0, 0);
    const int nk = C_ >> 5;                      // 16
    for (int i = 0; i < nk; ++i) {
        __syncthreads();
        if (i + 1 < nk) stage((i + 1) << 5, (i + 1) & 1);
        int buf = i & 1;

        frag8 bfrag[4], afrag[4];
        for (int ni = 0; ni < 4; ++ni)
            bfrag[ni] = *(const frag8*)(&Bs[buf][(wn + ni * 16 + l16) * 32 + ((quad * 8) ^ rsw8)]);
        for (int mi = 0; mi < 4; ++mi)
            afrag[mi] = *(const frag8*)(&As[buf][(wm + mi * 16 + l16) * 32 + ((quad * 8) ^ rsw8)]);

        for (int mi = 0; mi < 4; ++mi)
            for (int ni = 0; ni < 4; ++ni)
                acc[mi][ni] = __builtin_amdgcn_mfma_f32_16x16x32_bf16(
                    afrag[mi], bfrag[ni], acc[mi][ni], 0, 0, 0);
    }

    for (int ni = 0; ni < 4; ++ni) {
        int c0 = n0 + wn + ni * 16;
        float bv = bias[c0 + l16];
        int h = c0 / 192, rr = c0 % 192;
        if (rr >= 128) {
            int d = rr - 128 + l16;
            int bidx = m0 >> 10;
            unsigned short* vp = outV + (((size_t)bidx * NH + h) * HD + d) * S_
                               + (m0 & 1023) + wm + quad * 4;
            for (int mi = 0; mi < 4; ++mi) {
                uint2 pk;
                pk.x = pk2bf(acc[mi][ni][0] + bv, acc[mi][ni][1] + bv);
                pk.y = pk2bf(acc[mi][ni][2] + bv, acc[mi][ni][3] + bv);
                *(uint2*)(vp + mi * 16) = pk;
            }
        } else {
            float scl = (rr < 64) ? QSCL : 1.0f;   // q pre-scaled by log2e/8
            int colk = h * 128 + rr + l16;
            for (int mi = 0; mi < 4; ++mi)
                for (int r = 0; r < 4; ++r) {
                    int row = m0 + wm + mi * 16 + quad * 4 + r;
                    outA[(size_t)row * 1024 + colk] = f2bf((acc[mi][ni][r] + bv) * scl);
                }
        }
    }
}

// ---------------------------------------------------------------- out GEMM
// 64x128 tile, 512 blocks = 2/CU. BK=64 per barrier as two 32-wide
// sub-steps (4-buffer LDS, 48 KB) -> 8 barriers; gl_lds staging
// seg-swizzled; fused bias + residual, fp32 out.
__global__ __launch_bounds__(256) void gemm_out_kernel(
        const unsigned short* __restrict__ A,     // attn [8192][512]
        const unsigned short* __restrict__ Bt,    // woutT [512][512]
        const float* __restrict__ bias,
        const unsigned short* __restrict__ resid, // xn
        float* __restrict__ outF) {
    __shared__ unsigned short As[2][2][64 * 32];
    __shared__ unsigned short Bs[2][2][128 * 32];
    unsigned int flat = blockIdx.x;
    unsigned int nid = (flat & 7u) * 64u + (flat >> 3);   // bijective (512%8==0)
    int my = nid >> 2, mx = nid & 3;
    int m0 = my * 64, n0 = mx * 128;
    int t = threadIdx.x;
    int wid = t >> 6, lane = t & 63;
    int quad = lane >> 4, l16 = lane & 15;
    int wm = (wid >> 1) * 32, wn = (wid & 1) * 64;

    f32x4 acc[2][4];
    for (int mi = 0; mi < 2; ++mi)
        for (int ni = 0; ni < 4; ++ni) acc[mi][ni] = zero4();

    int srow = t >> 2;
    int sseg_sw = (t & 3) ^ ((t >> 3) & 3);
    auto stage = [&](int k0, int buf) {
        for (int s = 0; s < 2; ++s) {
            gl_lds(A + (size_t)(m0 + srow) * C_ + k0 + s * 32 + sseg_sw * 8,
                   &As[buf][s][(size_t)wid * 512]);
            for (int i = 0; i < 2; ++i)
                gl_lds(Bt + (size_t)(n0 + i * 64 + srow) * C_ + k0 + s * 32 + sseg_sw * 8,
                       &Bs[buf][s][(size_t)(i * 256 + wid * 64) * 8]);
        }
    };

    int rsw8 = ((l16 >> 1) & 3) * 8;

    stage(0, 0);
    const int nk = C_ >> 6;                      // 8 (BK=64 per barrier)
    for (int i = 0; i < nk; ++i) {
        __syncthreads();
        if (i + 1 < nk) stage((i + 1) << 6, (i + 1) & 1);
        int buf = i & 1;

        for (int s = 0; s < 2; ++s) {
            frag8 bfrag[4], afrag[2];
            for (int ni = 0; ni < 4; ++ni)
                bfrag[ni] = *(const frag8*)(&Bs[buf][s][(wn + ni * 16 + l16) * 32 + ((quad * 8) ^ rsw8)]);
            for (int mi = 0; mi < 2; ++mi)
                afrag[mi] = *(const frag8*)(&As[buf][s][(wm + mi * 16 + l16) * 32 + ((quad * 8) ^ rsw8)]);

            for (int mi = 0; mi < 2; ++mi)
                for (int ni = 0; ni < 4; ++ni)
                    acc[mi][ni] = __builtin_amdgcn_mfma_f32_16x16x32_bf16(
                        afrag[mi], bfrag[ni], acc[mi][ni], 0, 0, 0);
        }
    }

    for (int ni = 0; ni < 4; ++ni) {
        int col = n0 + wn + ni * 16 + l16;
        float bv = bias[col];
        for (int mi = 0; mi < 2; ++mi)
            for (int r = 0; r < 4; ++r) {
                int row = m0 + wm + mi * 16 + quad * 4 + r;
                float v = acc[mi][ni][r] + bv + bf2f(resid[(size_t)row * C_ + col]);
                outF[(size_t)row * C_ + col] = v;
            }
    }
}

// ---------------------------------------------------------------- attention
// 512 blocks (XCD-chunked), 4 waves x 32 q-rows (128 q/block), 64 keys/iter.
// Core: S^T=K@Q^T, P built in registers as PV A-frag under key relabeling
// sigma(kh,quad,r)=8*quad+4*kh+r, V staged with same permutation; K/V LDS
// 16B-seg XOR swizzle. l on VALU from packed P frag (lane holds 8 rounded P
// of q-row l16); quad-reduce at epilogue. No ones-MFMA.
__global__ __launch_bounds__(256) void attn_kernel(
        const unsigned short* __restrict__ kq,   // [b*s][h*128 + (q|k)]
        const unsigned short* __restrict__ vT,   // [b][h][d][s]
        unsigned short* __restrict__ attn_out) { // [b][s][512]
    int i = blockIdx.x;
    int xcd = i & 7, slot = i >> 3;              // slot 0..63
    int bh = xcd * 8 + (slot >> 3);              // 8 (b,h) pairs per XCD
    int qt = slot & 7;                           // 8 q-tiles of 128
    int b = bh >> 3, h = bh & 7;

    int t = threadIdx.x;
    int wid = t >> 6, lane = t & 63, quad = lane >> 4, l16 = lane & 15;
    int q0 = qt * 128 + wid * 32;

    __shared__ unsigned short Ks[2][2][2048];    // [buf][key-half 32][dh][key32][seg4x8] (swz)
    __shared__ unsigned short Vs[2][2][2048];    // [buf][key-half][d64][seg4x8] (swz)

    // Q B-fragments for both 16-row groups (one-time scattered load)
    const unsigned short* qrow0 = kq + ((size_t)b * S_ + q0 + l16) * 1024 + h * 128;
    const unsigned short* qrow1 = qrow0 + (size_t)16 * 1024;
    frag8 qf[2][2];
    qf[0][0] = *(const frag8*)(qrow0 + quad * 8);
    qf[0][1] = *(const frag8*)(qrow0 + 32 + quad * 8);
    qf[1][0] = *(const frag8*)(qrow1 + quad * 8);
    qf[1][1] = *(const frag8*)(qrow1 + 32 + quad * 8);

    f32x4 o[2][4];
    float lsum[2] = {0.f, 0.f};
    for (int g = 0; g < 2; ++g)
        for (int dt = 0; dt < 4; ++dt) o[g][dt] = zero4();

    const unsigned short* kbase = kq + (size_t)b * S_ * 1024 + h * 128 + 64;
    const unsigned short* vbase = vT + ((size_t)b * NH + h) * HD * S_;

    // K staging roles (gl_lds, wave-uniform linear LDS dest; fetch seg
    // permuted so LDS lands swizzled: seg_fetch = slot ^ ((local_row>>1)&3))
    int kdh = wid & 1, krh = wid >> 1;
    int krow = krh * 16 + (lane >> 2);
    int kseg = (lane & 3) ^ ((lane >> 3) & 3);
    // V staging roles (explicit load + permuted+swizzled b64 writes)
    int vd = wid * 16 + (lane >> 2);             // d row 0..63
    int vseg = lane & 3;                         // true-key segment (8 keys)
    int vkh = vseg >> 1, vsp = vseg & 1;
    int vsw = (lane >> 3) & 3;                   // (vd>>1)&3
    int vo1 = (((vsp * 2) ^ vsw) * 8) + vkh * 4;       // shorts
    int vo2 = (((vsp * 2 + 1) ^ vsw) * 8) + vkh * 4;   // shorts (+16B seg)

    int ksw = (l16 >> 1) & 3;                    // read-side swizzle

    auto stageK = [&](int j0, int buf, int half) {
        gl_lds(kbase + (size_t)(j0 + krow) * 1024 + kdh * 32 + kseg * 8,
               &Ks[buf][half][kdh * 1024 + krh * 512]);
    };
    auto loadV = [&](int j0) {
        return *(const uint4*)(vbase + (size_t)vd * S_ + j0 + vseg * 8);
    };
    auto writeV = [&](uint4 w, int buf, int half) {
        unsigned short* vdst = &Vs[buf][half][vd * 32];
        uint2 g1; g1.x = w.x; g1.y = w.y;
        uint2 g2; g2.x = w.z; g2.y = w.w;
        *(uint2*)(vdst + vo1) = g1;
        *(uint2*)(vdst + vo2) = g2;
    };

    stageK(0, 0, 0);  stageK(32, 0, 1);
    writeV(loadV(0), 0, 0);  writeV(loadV(32), 0, 1);

    for (int it = 0; it < S_ / 64; ++it) {
        int cur = it & 1, nxt = cur ^ 1;
        __syncthreads();                          // staging of cur visible
        uint4 vn0, vn1;
        bool more = (it < S_ / 64 - 1);
        if (more) {
            int jn = (it + 1) * 64;
            stageK(jn, nxt, 0);
            stageK(jn + 32, nxt, 1);
            vn0 = loadV(jn);
            vn1 = loadV(jn + 32);
        }

        for (int half = 0; half < 2; ++half) {
            // K frags from LDS (A-operand): A[m=key=kh*16+l16][k=d] (swz read)
            frag8 kf[2][2];
            for (int kh = 0; kh < 2; ++kh)
                for (int dh = 0; dh < 2; ++dh)
                    kf[kh][dh] = *(const frag8*)(&Ks[cur][half][dh * 1024
                        + (kh * 16 + l16) * 32 + ((quad ^ ksw) * 8)]);

            // V frags from LDS (permuted positions): B[n=d][k=pos=quad*8+j]
            frag8 vf[4];
            for (int dt = 0; dt < 4; ++dt)
                vf[dt] = *(const frag8*)(&Vs[cur][half][(dt * 16 + l16) * 32
                        + ((quad ^ ksw) * 8)]);

            for (int g = 0; g < 2; ++g) {
                // S^T = K @ Q^T : lane holds S^T[key=kh*16+quad*4+r][q=l16]
                f32x4 s0 = zero4(), s1 = zero4();
                __builtin_amdgcn_s_setprio(1);
                s0 = __builtin_amdgcn_mfma_f32_16x16x32_bf16(kf[0][0], qf[g][0], s0, 0, 0, 0);
                s0 = __builtin_amdgcn_mfma_f32_16x16x32_bf16(kf[0][1], qf[g][1], s0, 0, 0, 0);
                s1 = __builtin_amdgcn_mfma_f32_16x16x32_bf16(kf[1][0], qf[g][0], s1, 0, 0, 0);
                s1 = __builtin_amdgcn_mfma_f32_16x16x32_bf16(kf[1][1], qf[g][1], s1, 0, 0, 0);
                __builtin_amdgcn_s_setprio(0);

                // P A-frag in registers (relabeled positions)
                union { frag8 f; unsigned int u[4]; } pfu;
                pfu.u[0] = pk2bf(fexp2(s0[0]), fexp2(s0[1]));
                pfu.u[1] = pk2bf(fexp2(s0[2]), fexp2(s0[3]));
                pfu.u[2] = pk2bf(fexp2(s1[0]), fexp2(s1[1]));
                pfu.u[3] = pk2bf(fexp2(s1[2]), fexp2(s1[3]));

                // l partial on VALU: lane's 8 rounded P values belong to
                // q-row l16, keys quad*8+j (quad-reduce deferred to epilogue)
                float lacc = 0.f;
#pragma unroll
                for (int w2 = 0; w2 < 4; ++w2) {
                    union { unsigned int u; float f; } plo, phi;
                    plo.u = pfu.u[w2] << 16;
                    phi.u = pfu.u[w2] & 0xffff0000u;
                    lacc += plo.f + phi.f;
                }
                lsum[g] += lacc;

                __builtin_amdgcn_s_setprio(1);
                for (int dt = 0; dt < 4; ++dt)
                    o[g][dt] = __builtin_amdgcn_mfma_f32_16x16x32_bf16(pfu.f, vf[dt], o[g][dt], 0, 0, 0);
                __builtin_amdgcn_s_setprio(0);
            }
        }

        if (more) {
            writeV(vn0, nxt, 0);                  // visible after next barrier
            writeV(vn1, nxt, 1);
        }
    }

    // O C-layout: lane(quad,l16) holds O[q=g*16+quad*4+r][d=dt*16+l16].
    // lsum[g] holds the partial row-sum for q=l16 over this lane's quad's
    // key slots; reduce across quads, then fetch the value for row quad*4+r.
    for (int g = 0; g < 2; ++g) {
        float lq = lsum[g];
        lq += __shfl_xor(lq, 16);
        lq += __shfl_xor(lq, 32);                // all lanes: l[q=l16]
        for (int r = 0; r < 4; ++r) {
            float inv = 1.0f / __shfl(lq, quad * 4 + r);
            int qrw = q0 + g * 16 + quad * 4 + r;
            for (int dt = 0; dt < 4; ++dt) {
                int ch = h * HD + dt * 16 + l16;
                attn_out[((size_t)b * S_ + qrw) * C_ + ch] = f2bf(o[g][dt][r] * inv);
            }
        }
    }
}

// ---------------------------------------------------------------- launch
extern "C" void kernel_launch(void* const* d_in, const int* in_sizes, int n_in,
                              void* d_out, int out_size, void* d_ws, size_t ws_size,
                              hipStream_t stream) {
    const float* x        = (const float*)d_in[0];
    const float* gn_scale = (const float*)d_in[2];
    const float* gn_bias  = (const float*)d_in[3];
    const float* w_qkv    = (const float*)d_in[4];
    const float* b_qkv    = (const float*)d_in[5];
    const float* w_out    = (const float*)d_in[6];
    const float* b_out    = (const float*)d_in[7];
    float* out = (float*)d_out;

    char* ws = (char*)d_ws;
    unsigned short* xn    = (unsigned short*)(ws);                          // 8 MB
    unsigned short* kq    = (unsigned short*)(ws + ((size_t)8  << 20));     // 16 MB
    unsigned short* attn  = (unsigned short*)(ws + ((size_t)24 << 20));     // 8 MB
    unsigned short* vT    = (unsigned short*)(ws + ((size_t)32 << 20));     // 8 MB
    unsigned short* wqkvT = (unsigned short*)(ws + ((size_t)40 << 20));     // 1.5 MB
    unsigned short* woutT = (unsigned short*)(ws + ((size_t)40 << 20) + ((size_t)3 << 19)); // 0.5 MB

    prep_kernel<<<dim3(1280), 256, 0, stream>>>(
        w_qkv, w_out, wqkvT, woutT, x, gn_scale, gn_bias, xn);

    gemm_qkv_kernel<<<dim3(QKVC / 128, (B_ * S_) / 128), 256, 0, stream>>>(
        xn, wqkvT, b_qkv, kq, vT);

    attn_kernel<<<dim3(1024 / 2), 256, 0, stream>>>(kq, vT, attn);

    gemm_out_kernel<<<dim3(512), 256, 0, stream>>>(
        attn, woutT, b_out, xn, out);
}